// Round 6
// baseline (89.749 us; speedup 1.0000x reference)
//
#include <hip/hip_runtime.h>
#include <math.h>

#define N 64
#define F 64
#define W 40
#define D 512
#define LSM 9.0f
#define LLSE 6.0f
#define MARG 0.2f
#define ESTR 56    // Es row stride in halves (112 B -> every row 16B-aligned)
#define EWSZ 3600  // per-wave Es halves (max idx 63*56+63=3591 -> 3600)

typedef _Float16 f16x8 __attribute__((ext_vector_type(8)));
typedef _Float16 f16x4 __attribute__((ext_vector_type(4)));
typedef float f32x4 __attribute__((ext_vector_type(4)));

// layouts (halves), all linear now:
//  img_h per i: [64][512]                       (32768)
//  cap_h per j: [48][512], rows 40..47 = 0      (24576)
//  G_h  per j: [48][64], zero outside 40x40    (3072)

// ---------------- k_pre: grid 320 ----------------
// blocks [0,256): img convert fp16 + n1 (block = 16 rows of one image)
// blocks [256,320): cap convert fp16 + Gram via MFMA (block = one caption)
__global__ __launch_bounds__(256) void k_pre(
    const float* __restrict__ img, const float* __restrict__ cap,
    _Float16* __restrict__ img_h, _Float16* __restrict__ cap_h,
    _Float16* __restrict__ G_h, float* __restrict__ n1) {
  __shared__ __align__(16) _Float16 capT[4 * 48 * 128];  // 48 KB (cap blocks only)
  int t = threadIdx.x;
  int lane = t & 63;
  int b = blockIdx.x;
  if (b < 256) {
    int i = b >> 2;
    int f = ((b & 3) << 4) + (t >> 4);
    int q = t & 15;
    const float* row = img + ((size_t)i * F + f) * D + q * 32;
    _Float16* drow = img_h + ((size_t)i * F + f) * D + q * 32;
    float s = 0.f;
#pragma unroll
    for (int k = 0; k < 4; ++k) {
      float4 u = *(const float4*)(row + k * 8);
      float4 v = *(const float4*)(row + k * 8 + 4);
      s += u.x * u.x + u.y * u.y + u.z * u.z + u.w * u.w;
      s += v.x * v.x + v.y * v.y + v.z * v.z + v.w * v.w;
      f16x8 h;
      h[0] = (_Float16)u.x; h[1] = (_Float16)u.y; h[2] = (_Float16)u.z; h[3] = (_Float16)u.w;
      h[4] = (_Float16)v.x; h[5] = (_Float16)v.y; h[6] = (_Float16)v.z; h[7] = (_Float16)v.w;
      *(f16x8*)(drow + k * 8) = h;
    }
    s += __shfl_xor(s, 1);
    s += __shfl_xor(s, 2);
    s += __shfl_xor(s, 4);
    s += __shfl_xor(s, 8);
    if (q == 0) n1[i * F + f] = sqrtf(s);
  } else {
    int j = b - 256;
    int wv = t >> 6;
    const float* src = cap + (size_t)j * W * D;
    _Float16* dst = cap_h + (size_t)j * 24576;
#pragma unroll
    for (int k = 0; k < 12; ++k) {
      int slot = t + k * 256;  // 48 rows x 64 slots
      int w = slot >> 6, d = (slot & 63) * 8;
      float4 u = {0.f, 0.f, 0.f, 0.f}, v = {0.f, 0.f, 0.f, 0.f};
      if (w < W) {
        u = *(const float4*)(src + (size_t)w * D + d);
        v = *(const float4*)(src + (size_t)w * D + d + 4);
      }
      f16x8 h;
      h[0] = (_Float16)u.x; h[1] = (_Float16)u.y; h[2] = (_Float16)u.z; h[3] = (_Float16)u.w;
      h[4] = (_Float16)v.x; h[5] = (_Float16)v.y; h[6] = (_Float16)v.z; h[7] = (_Float16)v.w;
      int ch = d >> 7, din = d & 127;
      *(f16x8*)(dst + w * 512 + d) = h;  // linear global
      *(f16x8*)(capT + ch * 6144 + w * 128 + (din ^ ((w & 7) << 3))) = h;  // LDS swizzled
    }
    __syncthreads();
    int rlo = lane & 15, hi = lane >> 4;
    int koff = hi * 8, sw = (rlo & 7) << 3;
    _Float16* gb = G_h + (size_t)j * 3072;
    for (int tile = wv; tile < 9; tile += 4) {
      int mt = tile / 3, kt = tile % 3;
      f32x4 acc = (f32x4)0.f;
#pragma unroll
      for (int ks = 0; ks < 16; ++ks) {
        int kk = ks * 32 + koff;
        int ch = kk >> 7, din = (kk & 127) ^ sw;
        f16x8 af = *(const f16x8*)(capT + ch * 6144 + (mt * 16 + rlo) * 128 + din);
        f16x8 bf = *(const f16x8*)(capT + ch * 6144 + (kt * 16 + rlo) * 128 + din);
        acc = __builtin_amdgcn_mfma_f32_16x16x32_f16(af, bf, acc, 0, 0, 0);
      }
#pragma unroll
      for (int r = 0; r < 4; ++r) {
        int w = mt * 16 + hi * 4 + r, k = kt * 16 + rlo;
        float val = (w < W && k < W) ? acc[r] : 0.f;
        gb[w * 64 + k] = (_Float16)val;
      }
    }
    // zero G cols 48..63 (all 48 rows) - read as K-tail by k_main, x E=0
    for (int idx = t; idx < 96; idx += 256) {
      int w = idx >> 1, c8 = 48 + (idx & 1) * 8;
      *(f16x8*)(gb + w * 64 + c8) = (f16x8)(_Float16)0.f;
    }
  }
}

// ---------------- k_main: ONE WAVE = ONE (i,j) PAIR, zero barriers ----------------
// grid 1024 x 256thr: xcd = bid&7 pins an i-octet per XCD (img L2-hot);
// all operand reads direct from global (L2); only LDS = private Es per wave.
__global__ __launch_bounds__(256, 4) void k_main(
    const _Float16* __restrict__ img_h, const _Float16* __restrict__ cap_h,
    const int* __restrict__ imgL, const int* __restrict__ capL,
    const float* __restrict__ n1g, const _Float16* __restrict__ G_h,
    float* __restrict__ S) {
  __shared__ __align__(16) _Float16 Es[4][EWSZ];  // 28800 B

  int t = threadIdx.x;
  int lane = t & 63, wv = t >> 6;
  int rlo = lane & 15, hi = lane >> 4;
  int koff = hi * 8;

  int bid = blockIdx.x;
  int xcd = bid & 7, s0 = bid >> 3;
  int j = s0 & 63;
  int i = xcd * 8 + (s0 >> 6) * 4 + wv;

  int iL = imgL[i], cL = capL[j];
  _Float16* Ew = &Es[wv][0];

  // zero the whole private Es slice (covers row gaps + K-tail reads)
#pragma unroll
  for (int k = lane; k < EWSZ / 8; k += 64) ((f16x8*)Ew)[k] = (f16x8)(_Float16)0.f;

  float n1lane = n1g[i * F + lane];

  // ---- A-phase: A[w][f] = cap_w . img_f  (192 MFMA, all operands from L2) ----
  const _Float16* cb = cap_h + (size_t)j * 24576 + rlo * 512 + koff;
  const _Float16* ib = img_h + (size_t)i * 32768 + rlo * 512 + koff;
  f32x4 acc[3][4];
#pragma unroll
  for (int mt = 0; mt < 3; ++mt)
#pragma unroll
    for (int nt = 0; nt < 4; ++nt) acc[mt][nt] = (f32x4)0.f;

#pragma unroll
  for (int ks = 0; ks < 16; ++ks) {
    int kk = ks * 32;
    f16x8 af[3], bf[4];
#pragma unroll
    for (int mt = 0; mt < 3; ++mt) af[mt] = *(const f16x8*)(cb + mt * 8192 + kk);
#pragma unroll
    for (int nt = 0; nt < 4; ++nt) bf[nt] = *(const f16x8*)(ib + nt * 8192 + kk);
#pragma unroll
    for (int mt = 0; mt < 3; ++mt)
#pragma unroll
      for (int nt = 0; nt < 4; ++nt)
        acc[mt][nt] = __builtin_amdgcn_mfma_f32_16x16x32_f16(af[mt], bf[nt], acc[mt][nt], 0, 0, 0);
  }

  // ---- rnorm: rinv per w from sum_f leaky(A)^2 (f-masked) ----
  float rinv[3][4];
#pragma unroll
  for (int mt = 0; mt < 3; ++mt)
#pragma unroll
    for (int r = 0; r < 4; ++r) {
      float s = 0.f;
#pragma unroll
      for (int nt = 0; nt < 4; ++nt) {
        float a = acc[mt][nt][r];
        float l = a > 0.f ? a : 0.1f * a;
        s += ((nt * 16 + rlo) < iL) ? l * l : 0.f;
      }
#pragma unroll
      for (int d = 1; d < 16; d <<= 1) s += __shfl_xor(s, d);
      rinv[mt][r] = 1.f / (sqrtf(s) + 1e-8f);
    }

  // ---- fused softmax: logits bounded in [-9,9] -> no max subtraction ----
  float sn[4] = {0.f, 0.f, 0.f, 0.f};
#pragma unroll
  for (int mt = 0; mt < 3; ++mt)
#pragma unroll
    for (int nt = 0; nt < 4; ++nt) {
      f16x4 ev;
#pragma unroll
      for (int r = 0; r < 4; ++r) {
        int w = mt * 16 + hi * 4 + r;
        float a = acc[mt][nt][r];
        float l = a > 0.f ? a : 0.1f * a;
        float e = (w < cL) ? __expf(LSM * l * rinv[mt][r]) : 0.f;
        sn[nt] = fmaf(e, a, sn[nt]);
        ev[r] = (_Float16)e;
      }
      *(f16x4*)(Ew + (nt * 16 + rlo) * ESTR + mt * 16 + hi * 4) = ev;
    }
#pragma unroll
  for (int nt = 0; nt < 4; ++nt) {
    sn[nt] += __shfl_xor(sn[nt], 16);
    sn[nt] += __shfl_xor(sn[nt], 32);
  }

  // ---- P = E*G (24 MFMA; G from global, E from private LDS) ----
  const _Float16* gB = G_h + (size_t)j * 3072 + rlo * 64 + koff;
  f32x4 P[4][3];
#pragma unroll
  for (int mtl = 0; mtl < 4; ++mtl)
#pragma unroll
    for (int ntl = 0; ntl < 3; ++ntl) P[mtl][ntl] = (f32x4)0.f;
#pragma unroll
  for (int ks2 = 0; ks2 < 2; ++ks2) {
    int kk2 = ks2 * 32;
    f16x8 bfg[3];
#pragma unroll
    for (int ntl = 0; ntl < 3; ++ntl) bfg[ntl] = *(const f16x8*)(gB + ntl * 1024 + kk2);
#pragma unroll
    for (int mtl = 0; mtl < 4; ++mtl) {
      f16x8 af = *(const f16x8*)(Ew + (mtl * 16 + rlo) * ESTR + kk2 + koff);
#pragma unroll
      for (int ntl = 0; ntl < 3; ++ntl)
        P[mtl][ntl] = __builtin_amdgcn_mfma_f32_16x16x32_f16(af, bfg[ntl], P[mtl][ntl], 0, 0, 0);
    }
  }

  // ---- n2^2 = sum_w P.E per f; sim; LSE over f; one store per wave ----
  float ef = 0.f;
#pragma unroll
  for (int mtl = 0; mtl < 4; ++mtl) {
#pragma unroll
    for (int rr = 0; rr < 4; ++rr) {
      int fm = mtl * 16 + hi * 4 + rr;
      float n2s = 0.f;
#pragma unroll
      for (int ntl = 0; ntl < 3; ++ntl) {
        float evv = (float)Ew[fm * ESTR + ntl * 16 + rlo];
        n2s = fmaf(P[mtl][ntl][rr], evv, n2s);
      }
#pragma unroll
      for (int d = 1; d < 16; d <<= 1) n2s += __shfl_xor(n2s, d);
      float nm = __shfl(sn[mtl], hi * 4 + rr);
      float n1v = __shfl(n1lane, fm);
      float denom = n1v * sqrtf(fmaxf(n2s, 0.f));
      float sim = nm / fmaxf(denom, 1e-20f);
      ef += (fm < iL) ? __expf(LLSE * sim) : 0.f;
    }
  }
  ef += __shfl_xor(ef, 16);
  ef += __shfl_xor(ef, 32);
  if (lane == 0) S[(j << 6) + i] = __logf(ef) * (1.f / LLSE);
}

// ---------------- k_loss ----------------
__global__ void k_loss(const float* __restrict__ S, float* __restrict__ out) {
  __shared__ float red[128];
  int t = threadIdx.x;
  float m = -1e30f;
  if (t < 64) {
    int a = t;
    float da = S[a * N + a];
    for (int b = 0; b < N; ++b)
      if (b != a) m = fmaxf(m, MARG + S[a * N + b] - da);
  } else {
    int b = t - 64;
    float db = S[b * N + b];
    for (int a = 0; a < N; ++a)
      if (a != b) m = fmaxf(m, MARG + S[a * N + b] - db);
  }
  m = fmaxf(m, 0.f);
  red[t] = m;
  __syncthreads();
  if (t == 0) {
    float s = 0.f;
    for (int k = 0; k < 128; ++k) s += red[k];
    *out = s;
  }
}

extern "C" void kernel_launch(void* const* d_in, const int* in_sizes, int n_in,
                              void* d_out, int out_size, void* d_ws, size_t ws_size,
                              hipStream_t stream) {
  const float* img = (const float*)d_in[0];
  const float* cap = (const float*)d_in[1];
  const int* imgL = (const int*)d_in[2];
  const int* capL = (const int*)d_in[3];

  char* wsb = (char*)d_ws;
  float* n1 = (float*)wsb;                                // 16 KB
  float* S = (float*)(wsb + 16384);                       // 16 KB
  _Float16* img_h = (_Float16*)(wsb + 32768);             // 4 MB
  _Float16* cap_h = (_Float16*)(wsb + 32768 + 4194304);   // 3 MB
  _Float16* G_h = (_Float16*)(wsb + 32768 + 4194304 + 3145728);  // 384 KB

  k_pre<<<320, 256, 0, stream>>>(img, cap, img_h, cap_h, G_h, n1);
  k_main<<<1024, 256, 0, stream>>>(img_h, cap_h, imgL, capL, n1, G_h, S);
  k_loss<<<1, 128, 0, stream>>>(S, (float*)d_out);
}